// Round 21
// baseline (64929.327 us; speedup 1.0000x reference)
//
#include <hip/hip_runtime.h>

constexpr int kB = 64, kS = 2048, kD = 512, kL = 4;
constexpr int kR = 8;                                  // ring depth (time slots)
constexpr int RING_F = kR * kL * kB * kD;              // 4 MB
constexpr int ZBUF_F = kB * kD;                        // 128 KB
constexpr int CNT_N  = kL * 8 * kS;                    // 256 KB
constexpr long PACK_F2 = (long)kL * kD * kD;           // 1M float2 = 8 MB
constexpr size_t NEED_BASE = (size_t)(RING_F + ZBUF_F + CNT_N) * 4;
constexpr size_t NEED_PACK = NEED_BASE + (size_t)PACK_F2 * 8 + 4096;

// CONFIRMED reference tanh (R15/R16): XLA EmitFastTanh with_fma=true.
__device__ __forceinline__ float tanh_ref(float x0) {
#pragma clang fp contract(off)
  const float kMax = 7.99881172180175781f;
  float xc = fminf(fmaxf(x0, -kMax), kMax);
  float x2 = xc * xc;
  float p = -2.76076847742355e-16f;
  p = fmaf(x2, p, 2.00018790482477e-13f);
  p = fmaf(x2, p, -8.60467152213735e-11f);
  p = fmaf(x2, p, 5.12229709037114e-08f);
  p = fmaf(x2, p, 1.48572235717979e-05f);
  p = fmaf(x2, p, 6.37261928875436e-04f);
  p = fmaf(x2, p, 4.89352455891786e-03f);
  float num = xc * p;
  float q = 1.19825839466702e-06f;
  q = fmaf(x2, q, 1.18534705686654e-04f);
  q = fmaf(x2, q, 2.26843463243900e-03f);
  q = fmaf(x2, q, 4.89352518554385e-03f);
  float r = num / q;
  return (fabsf(x0) < 0.0004f) ? x0 : r;
}

__global__ void prep_zero(float* __restrict__ zbuf, unsigned* __restrict__ cnt) {
  const int gid = blockIdx.x * blockDim.x + threadIdx.x;
  for (int i = gid; i < ZBUF_F; i += gridDim.x * blockDim.x) zbuf[i] = 0.f;
  for (int i = gid; i < CNT_N; i += gridDim.x * blockDim.x) cnt[i] = 0u;
}

// pack: pk[(l*kD + k)*kD + j] = {W[l][k][j], U[l][k][j]} (bit-copy)
__global__ void pack_wu(const float* __restrict__ W, const float* __restrict__ U,
                        float2* __restrict__ pk) {
  const long gid = (long)blockIdx.x * blockDim.x + threadIdx.x;
  for (long i = gid; i < PACK_F2; i += (long)gridDim.x * blockDim.x)
    pk[i] = make_float2(W[i], U[i]);
}

__device__ __forceinline__ unsigned cnt_ld(const unsigned* p) {
  return __hip_atomic_load(p, __ATOMIC_RELAXED, __HIP_MEMORY_SCOPE_AGENT);
}

// broadcast lane kk of a float VGPR to all lanes (bit-exact pass-through)
__device__ __forceinline__ float lane_bcast(float v, int kk) {
  return __uint_as_float(__builtin_amdgcn_readlane(__float_as_uint(v), kk));
}

__device__ __forceinline__ void loadw16(float2 (&buf)[16],
                                        const float2* __restrict__ pkc, int g) {
#pragma unroll
  for (int q = 0; q < 16; ++q) buf[q] = pkc[(long)(g * 16 + q) * kD];
}

__device__ __forceinline__ void consume16(const float2 (&buf)[16], int kloc,
                                          float vi0, float vi1, float vh0, float vh1,
                                          float& dw0, float& dw1,
                                          float& du0, float& du1) {
#pragma clang fp contract(off)
#pragma unroll
  for (int q = 0; q < 16; ++q) {
    const int kk = kloc + q;
    const float ai0 = lane_bcast(vi0, kk);
    const float ai1 = lane_bcast(vi1, kk);
    const float ah0 = lane_bcast(vh0, kk);
    const float ah1 = lane_bcast(vh1, kk);
    dw0 = fmaf(ai0, buf[q].x, dw0);
    dw1 = fmaf(ai1, buf[q].x, dw1);
    du0 = fmaf(ah0, buf[q].y, du0);
    du1 = fmaf(ah1, buf[q].y, du1);
  }
}

// grid 256 = l(4) x bg(8) x jg(8); block 256 = 4 waves(bq) x 64 lanes(jl).
// Thread -> outputs (b0,j),(b0+1,j). No LDS; packed W/U float2 stream with
// 16-deep double-buffered register pipeline; acts via readlane broadcast.
__global__ __launch_bounds__(256, 1) void rnn_pipe4(
    const float* __restrict__ x, const float2* __restrict__ wupk,
    const float* __restrict__ bias, float* __restrict__ out,
    float* __restrict__ ring, float* __restrict__ zbuf,
    unsigned* __restrict__ cnt) {
  const int tid = threadIdx.x, bid = blockIdx.x;
  const int l  = bid >> 6;
  const int bg = (bid >> 3) & 7;
  const int jg = bid & 7;
  const int jl = tid & 63;
  const int bq = tid >> 6;
  const int j  = jg * 64 + jl;
  const int b0 = bg * 8 + bq * 2;
  const int b1 = b0 + 1;

  const float2* pkc = wupk + (long)l * kD * kD + j;  // element (k): pkc[k*kD]
  const float bv = bias[l * kD + j];

  const unsigned* cSibling = cnt + ((long)l * 8 + bg) * kS;
  const unsigned* cBelow   = (l > 0) ? cnt + ((long)(l - 1) * 8 + bg) * kS : nullptr;
  const unsigned* cAbove   = (l < kL - 1) ? cnt + ((long)(l + 1) * 8 + bg) * kS : nullptr;
  unsigned* cMine = cnt + ((long)l * 8 + bg) * kS;

  for (int t = 0; t < kS; ++t) {
    if (tid == 0) {
      if (t > 0)             while (cnt_ld(&cSibling[t - 1]) < 8u) __builtin_amdgcn_s_sleep(1);
      if (l > 0)             while (cnt_ld(&cBelow[t]) < 8u)       __builtin_amdgcn_s_sleep(1);
      if (cAbove && t >= kR) while (cnt_ld(&cAbove[t - kR]) < 8u)  __builtin_amdgcn_s_sleep(1);
      __threadfence();
    }
    __syncthreads();

    const int slot  = t & (kR - 1);
    const int slotP = (t - 1) & (kR - 1);
    const float* i0row, *i1row;
    if (l == 0) {
      i0row = x + ((long)b0 * kS + t) * kD;
      i1row = x + ((long)b1 * kS + t) * kD;
    } else {
      i0row = ring + (((long)slot * kL + (l - 1)) * kB + b0) * (long)kD;
      i1row = i0row + kD;
    }
    const float* h0row = (t == 0)
        ? zbuf + (long)b0 * kD
        : ring + (((long)slotP * kL + l) * kB + b0) * (long)kD;
    const float* h1row = h0row + kD;

    float dw0, dw1, du0, du1;
    {
#pragma clang fp contract(off)
      dw0 = 0.f; dw1 = 0.f; du0 = 0.f; du1 = 0.f;
      float2 bufA[16], bufB[16];
      loadw16(bufA, pkc, 0);
      float ni0 = i0row[jl], ni1 = i1row[jl];
      float nh0 = h0row[jl], nh1 = h1row[jl];
      float vi0 = 0.f, vi1 = 0.f, vh0 = 0.f, vh1 = 0.f;
      for (int gp = 0; gp < 16; ++gp) {
        const int g0 = gp * 2, g1 = g0 + 1;
        if ((g0 & 3) == 0) {  // new 64-k act chunk (uniform branch)
          vi0 = ni0; vi1 = ni1; vh0 = nh0; vh1 = nh1;
          const int ch = g0 >> 2;
          if (ch < 7) {
            const int nb = (ch + 1) * 64 + jl;
            ni0 = i0row[nb]; ni1 = i1row[nb];
            nh0 = h0row[nb]; nh1 = h1row[nb];
          }
        }
        loadw16(bufB, pkc, g1);
        consume16(bufA, (g0 & 3) * 16, vi0, vi1, vh0, vh1, dw0, dw1, du0, du1);
        if (g1 < 31) loadw16(bufA, pkc, g1 + 1);
        consume16(bufB, (g1 & 3) * 16, vi0, vi1, vh0, vh1, dw0, dw1, du0, du1);
      }
    }
    float z0, z1;
    {
#pragma clang fp contract(off)
      z0 = (dw0 + du0) + bv;
      z1 = (dw1 + du1) + bv;
    }
    const float h0 = tanh_ref(z0);
    const float h1 = tanh_ref(z1);

    float* ho = ring + (((long)slot * kL + l) * kB) * (long)kD;
    ho[(long)b0 * kD + j] = h0;
    ho[(long)b1 * kD + j] = h1;
    if (l == kL - 1) {
      out[((long)b0 * kS + t) * kD + j] = h0;
      out[((long)b1 * kS + t) * kD + j] = h1;
    }

    __syncthreads();
    if (tid == 0) {
      __threadfence();
      atomicAdd(&cMine[t], 1u);
    }
  }
}

// ---------- fallback: R20 kernel (proven 48.9 ms) ----------
__global__ __launch_bounds__(256, 1) void rnn_pipe3(
    const float* __restrict__ x, const float* __restrict__ Wh,
    const float* __restrict__ Uh, const float* __restrict__ bias,
    float* __restrict__ out, float* __restrict__ ring,
    float* __restrict__ zbuf, unsigned* __restrict__ cnt) {
  const int tid = threadIdx.x, bid = blockIdx.x;
  const int l  = bid >> 6;
  const int bg = (bid >> 3) & 7;
  const int jg = bid & 7;
  const int jl = tid & 63;
  const int bq = tid >> 6;
  const int j  = jg * 64 + jl;
  const int b0 = bg * 8 + bq * 2;
  const int b1 = b0 + 1;
  const float* Wcol = Wh + (long)l * kD * kD + j;
  const float* Ucol = Uh + (long)l * kD * kD + j;
  const float bv = bias[l * kD + j];
  const unsigned* cSibling = cnt + ((long)l * 8 + bg) * kS;
  const unsigned* cBelow   = (l > 0) ? cnt + ((long)(l - 1) * 8 + bg) * kS : nullptr;
  const unsigned* cAbove   = (l < kL - 1) ? cnt + ((long)(l + 1) * 8 + bg) * kS : nullptr;
  unsigned* cMine = cnt + ((long)l * 8 + bg) * kS;
  for (int t = 0; t < kS; ++t) {
    if (tid == 0) {
      if (t > 0)             while (cnt_ld(&cSibling[t - 1]) < 8u) __builtin_amdgcn_s_sleep(1);
      if (l > 0)             while (cnt_ld(&cBelow[t]) < 8u)       __builtin_amdgcn_s_sleep(1);
      if (cAbove && t >= kR) while (cnt_ld(&cAbove[t - kR]) < 8u)  __builtin_amdgcn_s_sleep(1);
      __threadfence();
    }
    __syncthreads();
    const int slot  = t & (kR - 1);
    const int slotP = (t - 1) & (kR - 1);
    const float* i0row, *i1row;
    if (l == 0) {
      i0row = x + ((long)b0 * kS + t) * kD;
      i1row = x + ((long)b1 * kS + t) * kD;
    } else {
      i0row = ring + (((long)slot * kL + (l - 1)) * kB + b0) * (long)kD;
      i1row = i0row + kD;
    }
    const float* h0row = (t == 0)
        ? zbuf + (long)b0 * kD
        : ring + (((long)slotP * kL + l) * kB + b0) * (long)kD;
    const float* h1row = h0row + kD;
    float dw0, dw1, du0, du1;
    {
#pragma clang fp contract(off)
      dw0 = 0.f; dw1 = 0.f; du0 = 0.f; du1 = 0.f;
      float ni0 = i0row[jl], ni1 = i1row[jl];
      float nh0 = h0row[jl], nh1 = h1row[jl];
      for (int ch = 0; ch < 8; ++ch) {
        const float vi0 = ni0, vi1 = ni1, vh0 = nh0, vh1 = nh1;
        if (ch < 7) {
          const int nb = (ch + 1) * 64 + jl;
          ni0 = i0row[nb]; ni1 = i1row[nb];
          nh0 = h0row[nb]; nh1 = h1row[nb];
        }
        const int base = ch * 64;
#pragma unroll
        for (int kk = 0; kk < 64; ++kk) {
          const float wv = Wcol[(long)(base + kk) * kD];
          const float uv = Ucol[(long)(base + kk) * kD];
          dw0 = fmaf(lane_bcast(vi0, kk), wv, dw0);
          dw1 = fmaf(lane_bcast(vi1, kk), wv, dw1);
          du0 = fmaf(lane_bcast(vh0, kk), uv, du0);
          du1 = fmaf(lane_bcast(vh1, kk), uv, du1);
        }
      }
    }
    float z0, z1;
    {
#pragma clang fp contract(off)
      z0 = (dw0 + du0) + bv;
      z1 = (dw1 + du1) + bv;
    }
    const float h0 = tanh_ref(z0);
    const float h1 = tanh_ref(z1);
    float* ho = ring + (((long)slot * kL + l) * kB) * (long)kD;
    ho[(long)b0 * kD + j] = h0;
    ho[(long)b1 * kD + j] = h1;
    if (l == kL - 1) {
      out[((long)b0 * kS + t) * kD + j] = h0;
      out[((long)b1 * kS + t) * kD + j] = h1;
    }
    __syncthreads();
    if (tid == 0) {
      __threadfence();
      atomicAdd(&cMine[t], 1u);
    }
  }
}

extern "C" void kernel_launch(void* const* d_in, const int* in_sizes, int n_in,
                              void* d_out, int out_size, void* d_ws, size_t ws_size,
                              hipStream_t stream) {
  const float* x    = (const float*)d_in[0];
  const float* Wh   = (const float*)d_in[1];
  const float* Uh   = (const float*)d_in[2];
  const float* bias = (const float*)d_in[3];
  float* out = (float*)d_out;
  float* ws  = (float*)d_ws;

  float* ring = ws;
  float* zbuf = ws + RING_F;
  unsigned* cnt = (unsigned*)(zbuf + ZBUF_F);

  prep_zero<<<128, 256, 0, stream>>>(zbuf, cnt);

  if (ws_size >= NEED_PACK) {
    float2* pk = (float2*)((char*)ws + NEED_BASE);
    pack_wu<<<512, 256, 0, stream>>>(Wh, Uh, pk);
    void* args[] = {(void*)&x, (void*)&pk, (void*)&bias, (void*)&out,
                    (void*)&ring, (void*)&zbuf, (void*)&cnt};
    hipLaunchCooperativeKernel((void*)rnn_pipe4, dim3(256), dim3(256), args, 0,
                               stream);
  } else {
    void* args[] = {(void*)&x, (void*)&Wh, (void*)&Uh, (void*)&bias,
                    (void*)&out, (void*)&ring, (void*)&zbuf, (void*)&cnt};
    hipLaunchCooperativeKernel((void*)rnn_pipe3, dim3(256), dim3(256), args, 0,
                               stream);
  }
}